// Round 1
// baseline (1293.558 us; speedup 1.0000x reference)
//
#include <hip/hip_runtime.h>
#include <hip/hip_fp16.h>

// ---- problem constants ----
#define BTOK  4096
#define D_IN  1024
#define D_HID 4096
#define D_OUT 1024
#define NE    8
// TOP_K = 2

typedef _Float16 half8 __attribute__((ext_vector_type(8)));
typedef float    floatx4 __attribute__((ext_vector_type(4)));

// GEMM tiling
#define BM 128
#define BN 128
#define BK 32
#define LDSTR 40   // fp16 stride (80 B = 16B-aligned rows, banks spread)

// ---- ws layout (bytes) ----
// xh   : fp16 x               [4096*1024]        @ 0          (8,388,608)
// h    : fp16 hidden          [(8192+128)*4096]  @ 8388608    (68,157,440)
// t2i  : int  top2 idx        [4096*2]           @ 76546048   (32,768)
// t2w  : f32  top2 weight     [4096*2]           @ 76578816   (32,768)
// ptok : int  pair token      [8192+128]         @ 76611584   (33,280)
// pw   : f32  pair weight     [8192+128]         @ 76644864   (33,280)
// meta : cnt[8],cursor[8],offs[8] int, usage[8] f32 @ 76678144 (128)
// total ~76.7 MB

// ---------------- convert x to fp16 ----------------
__global__ void convert_x_kernel(const float* __restrict__ x, _Float16* __restrict__ xh) {
    int i = (blockIdx.x * 256 + threadIdx.x) * 8;
    float4 a = *(const float4*)(x + i);
    float4 b = *(const float4*)(x + i + 4);
    half8 v;
    v[0] = (_Float16)a.x; v[1] = (_Float16)a.y; v[2] = (_Float16)a.z; v[3] = (_Float16)a.w;
    v[4] = (_Float16)b.x; v[5] = (_Float16)b.y; v[6] = (_Float16)b.z; v[7] = (_Float16)b.w;
    *(half8*)(xh + i) = v;
}

// ---------------- gating: logits (fp64 acc), top-2, softmax, usage ----------------
__global__ void gating_kernel(const float* __restrict__ x, const float* __restrict__ Wg,
                              const float* __restrict__ bg,
                              int* __restrict__ t2i, float* __restrict__ t2w,
                              int* __restrict__ cnt, float* __restrict__ usage) {
    __shared__ float susage[NE];
    int tid = threadIdx.x;
    if (tid < NE) susage[tid] = 0.f;
    __syncthreads();
    int wv = tid >> 6, lane = tid & 63;
    for (int tt = 0; tt < 4; ++tt) {
        int t = blockIdx.x * 16 + wv * 4 + tt;
        double part[NE];
        #pragma unroll
        for (int e = 0; e < NE; ++e) part[e] = 0.0;
        for (int i = lane; i < D_IN; i += 64) {
            double xv = (double)x[(size_t)t * D_IN + i];
            #pragma unroll
            for (int e = 0; e < NE; ++e) part[e] += xv * (double)Wg[i * NE + e];
        }
        #pragma unroll
        for (int e = 0; e < NE; ++e) {
            #pragma unroll
            for (int s = 32; s > 0; s >>= 1) part[e] += __shfl_xor(part[e], s, 64);
        }
        if (lane == 0) {
            float l[NE];
            #pragma unroll
            for (int e = 0; e < NE; ++e) l[e] = (float)part[e] + bg[e];
            // full softmax for load-balance usage
            float M = l[0];
            #pragma unroll
            for (int e = 1; e < NE; ++e) M = fmaxf(M, l[e]);
            float s = 0.f, g[NE];
            #pragma unroll
            for (int e = 0; e < NE; ++e) { g[e] = __expf(l[e] - M); s += g[e]; }
            float inv = 1.f / s;
            #pragma unroll
            for (int e = 0; e < NE; ++e) atomicAdd(&susage[e], g[e] * inv);
            // top-2 (ties -> lower index first, matches lax.top_k)
            int i0 = 0; float b0 = l[0];
            #pragma unroll
            for (int e = 1; e < NE; ++e) if (l[e] > b0) { b0 = l[e]; i0 = e; }
            int i1 = -1; float b1v = -1e30f;
            #pragma unroll
            for (int e = 0; e < NE; ++e) if (e != i0 && l[e] > b1v) { b1v = l[e]; i1 = e; }
            float w0 = 1.f / (1.f + expf(b1v - b0));
            t2i[2 * t] = i0; t2i[2 * t + 1] = i1;
            t2w[2 * t] = w0; t2w[2 * t + 1] = 1.f - w0;
            atomicAdd(&cnt[i0], 1);
            atomicAdd(&cnt[i1], 1);
        }
    }
    __syncthreads();
    if (tid < NE) atomicAdd(&usage[tid], susage[tid]);
}

// ---------------- scan + loss ----------------
__global__ void scan_kernel(const int* __restrict__ cnt, int* __restrict__ offs,
                            int* __restrict__ cursor, const float* __restrict__ usage,
                            float* __restrict__ out_loss) {
    if (threadIdx.x == 0) {
        int run = 0;
        for (int e = 0; e < NE; ++e) { offs[e] = run; cursor[e] = run; run += cnt[e]; }
        float loss = 0.f;
        for (int e = 0; e < NE; ++e) { float u = usage[e] / (float)BTOK; loss += u * u; }
        out_loss[0] = (float)NE * loss;
    }
}

// ---------------- scatter pairs into per-expert lists ----------------
__global__ void scatter_kernel(const int* __restrict__ t2i, const float* __restrict__ t2w,
                               int* __restrict__ cursor, int* __restrict__ ptok,
                               float* __restrict__ pw) {
    int t = blockIdx.x * blockDim.x + threadIdx.x;
    if (t >= BTOK) return;
    #pragma unroll
    for (int k = 0; k < 2; ++k) {
        int e = t2i[2 * t + k];
        int slot = atomicAdd(&cursor[e], 1);
        ptok[slot] = t;
        pw[slot] = t2w[2 * t + k];
    }
}

// ---------------- GEMM1: h = relu(x[tok] @ W1[e] + b1[e]) ----------------
__global__ __launch_bounds__(256, 2)
void gemm1_kernel(const _Float16* __restrict__ xh, const float* __restrict__ W1,
                  const float* __restrict__ b1, _Float16* __restrict__ h,
                  const int* __restrict__ cnt, const int* __restrict__ offs,
                  const int* __restrict__ ptok) {
    int e = blockIdx.z;
    int cnte = cnt[e];
    int row0 = blockIdx.x * BM;
    if (row0 >= cnte) return;
    int n0 = blockIdx.y * BN;
    int off = offs[e];

    __shared__ _Float16 Asm[BM * LDSTR];
    __shared__ _Float16 Bsm[BN * LDSTR];

    int tid = threadIdx.x;
    // A staging: tasks (row, chunk) — rows r=tid>>2 and r+64, chunk=tid&3 (8 fp16 each)
    int arow = tid >> 2, achunk = tid & 3;
    int p0 = row0 + arow, p1 = p0 + 64;
    int tok0 = ptok[off + min(p0, cnte - 1)];
    int tok1 = ptok[off + min(p1, cnte - 1)];
    const _Float16* aptr0 = xh + (size_t)tok0 * D_IN + achunk * 8;
    const _Float16* aptr1 = xh + (size_t)tok1 * D_IN + achunk * 8;

    // B staging: n=tid&127, ko = (tid>>7) + {0,2}
    int bn = tid & 127;
    const float* wbase = W1 + (size_t)e * D_IN * D_HID + (size_t)(n0 + bn);

    floatx4 acc[4][4] = {};
    int lane = tid & 63;
    int wvid = tid >> 6;
    int wm = (wvid & 1) * 64, wn = (wvid >> 1) * 64;
    int lr = lane & 15, lq = lane >> 4;

    for (int k0 = 0; k0 < D_IN; k0 += BK) {
        __syncthreads();
        half8 av0 = *(const half8*)(aptr0 + k0);
        half8 av1 = *(const half8*)(aptr1 + k0);
        *(half8*)&Asm[arow * LDSTR + achunk * 8] = av0;
        *(half8*)&Asm[(arow + 64) * LDSTR + achunk * 8] = av1;
        #pragma unroll
        for (int kop = 0; kop < 2; ++kop) {
            int ko = (tid >> 7) + kop * 2;
            const float* wp = wbase + (size_t)(k0 + ko * 8) * D_HID;
            half8 hv;
            #pragma unroll
            for (int j = 0; j < 8; ++j) hv[j] = (_Float16)wp[(size_t)j * D_HID];
            *(half8*)&Bsm[bn * LDSTR + ko * 8] = hv;
        }
        __syncthreads();
        half8 af[4], bf[4];
        #pragma unroll
        for (int f = 0; f < 4; ++f) {
            af[f] = *(const half8*)&Asm[(wm + f * 16 + lr) * LDSTR + lq * 8];
            bf[f] = *(const half8*)&Bsm[(wn + f * 16 + lr) * LDSTR + lq * 8];
        }
        #pragma unroll
        for (int mf = 0; mf < 4; ++mf)
            #pragma unroll
            for (int nf = 0; nf < 4; ++nf)
                acc[mf][nf] = __builtin_amdgcn_mfma_f32_16x16x32_f16(af[mf], bf[nf], acc[mf][nf], 0, 0, 0);
    }

    const float* b1e = b1 + (size_t)e * D_HID + n0;
    #pragma unroll
    for (int mf = 0; mf < 4; ++mf) {
        #pragma unroll
        for (int v = 0; v < 4; ++v) {
            int r = wm + mf * 16 + lq * 4 + v;
            int p = row0 + r;
            if (p < cnte) {
                _Float16* hrow = h + (size_t)(off + p) * D_HID + n0;
                #pragma unroll
                for (int nf = 0; nf < 4; ++nf) {
                    int c = wn + nf * 16 + lr;
                    float val = acc[mf][nf][v] + b1e[c];
                    hrow[c] = (_Float16)fmaxf(val, 0.f);
                }
            }
        }
    }
}

// ---------------- GEMM2: out[tok] += w * (h @ W2[e] + b2[e]) ----------------
__global__ __launch_bounds__(256, 2)
void gemm2_kernel(const _Float16* __restrict__ h, const float* __restrict__ W2,
                  const float* __restrict__ b2, const float* __restrict__ pw,
                  const int* __restrict__ ptok, const int* __restrict__ cnt,
                  const int* __restrict__ offs, float* __restrict__ out) {
    int e = blockIdx.z;
    int cnte = cnt[e];
    int row0 = blockIdx.x * BM;
    if (row0 >= cnte) return;
    int n0 = blockIdx.y * BN;
    int off = offs[e];

    __shared__ _Float16 Asm[BM * LDSTR];
    __shared__ _Float16 Bsm[BN * LDSTR];

    int tid = threadIdx.x;
    int arow = tid >> 2, achunk = tid & 3;
    int p0 = row0 + arow, p1 = p0 + 64;
    const _Float16* aptr0 = h + (size_t)(off + min(p0, cnte - 1)) * D_HID + achunk * 8;
    const _Float16* aptr1 = h + (size_t)(off + min(p1, cnte - 1)) * D_HID + achunk * 8;

    int bn = tid & 127;
    const float* wbase = W2 + (size_t)e * D_HID * D_OUT + (size_t)(n0 + bn);

    floatx4 acc[4][4] = {};
    int lane = tid & 63;
    int wvid = tid >> 6;
    int wm = (wvid & 1) * 64, wn = (wvid >> 1) * 64;
    int lr = lane & 15, lq = lane >> 4;

    for (int k0 = 0; k0 < D_HID; k0 += BK) {
        __syncthreads();
        half8 av0 = *(const half8*)(aptr0 + k0);
        half8 av1 = *(const half8*)(aptr1 + k0);
        *(half8*)&Asm[arow * LDSTR + achunk * 8] = av0;
        *(half8*)&Asm[(arow + 64) * LDSTR + achunk * 8] = av1;
        #pragma unroll
        for (int kop = 0; kop < 2; ++kop) {
            int ko = (tid >> 7) + kop * 2;
            const float* wp = wbase + (size_t)(k0 + ko * 8) * D_OUT;
            half8 hv;
            #pragma unroll
            for (int j = 0; j < 8; ++j) hv[j] = (_Float16)wp[(size_t)j * D_OUT];
            *(half8*)&Bsm[bn * LDSTR + ko * 8] = hv;
        }
        __syncthreads();
        half8 af[4], bf[4];
        #pragma unroll
        for (int f = 0; f < 4; ++f) {
            af[f] = *(const half8*)&Asm[(wm + f * 16 + lr) * LDSTR + lq * 8];
            bf[f] = *(const half8*)&Bsm[(wn + f * 16 + lr) * LDSTR + lq * 8];
        }
        #pragma unroll
        for (int mf = 0; mf < 4; ++mf)
            #pragma unroll
            for (int nf = 0; nf < 4; ++nf)
                acc[mf][nf] = __builtin_amdgcn_mfma_f32_16x16x32_f16(af[mf], bf[nf], acc[mf][nf], 0, 0, 0);
    }

    const float* b2e = b2 + (size_t)e * D_OUT + n0;
    #pragma unroll
    for (int mf = 0; mf < 4; ++mf) {
        #pragma unroll
        for (int v = 0; v < 4; ++v) {
            int r = wm + mf * 16 + lq * 4 + v;
            int p = row0 + r;
            if (p < cnte) {
                int tokp = ptok[off + p];
                float wgt = pw[off + p];
                float* orow = out + (size_t)tokp * D_OUT + n0;
                #pragma unroll
                for (int nf = 0; nf < 4; ++nf) {
                    int c = wn + nf * 16 + lr;
                    float val = (acc[mf][nf][v] + b2e[c]) * wgt;
                    atomicAdd(&orow[c], val);
                }
            }
        }
    }
}

extern "C" void kernel_launch(void* const* d_in, const int* in_sizes, int n_in,
                              void* d_out, int out_size, void* d_ws, size_t ws_size,
                              hipStream_t stream) {
    const float* x  = (const float*)d_in[0];
    const float* Wg = (const float*)d_in[1];
    const float* bg = (const float*)d_in[2];
    const float* W1 = (const float*)d_in[3];
    const float* b1 = (const float*)d_in[4];
    const float* W2 = (const float*)d_in[5];
    const float* b2 = (const float*)d_in[6];
    float* out = (float*)d_out;

    char* ws = (char*)d_ws;
    _Float16* xh  = (_Float16*)(ws);
    _Float16* h   = (_Float16*)(ws + 8388608);
    int*      t2i = (int*)(ws + 76546048);
    float*    t2w = (float*)(ws + 76578816);
    int*      ptok = (int*)(ws + 76611584);
    float*    pw   = (float*)(ws + 76644864);
    int*      meta = (int*)(ws + 76678144);
    int* cnt = meta; int* cursor = meta + 8; int* offs = meta + 16;
    float* usage = (float*)(meta + 24);

    hipMemsetAsync(d_out, 0, (size_t)((size_t)BTOK * D_OUT + 1) * sizeof(float), stream);
    hipMemsetAsync(meta, 0, 128, stream);

    convert_x_kernel<<<2048, 256, 0, stream>>>(x, xh);
    gating_kernel<<<256, 256, 0, stream>>>(x, Wg, bg, t2i, t2w, cnt, usage);
    scan_kernel<<<1, 64, 0, stream>>>(cnt, offs, cursor, usage, out + (size_t)BTOK * D_OUT);
    scatter_kernel<<<16, 256, 0, stream>>>(t2i, t2w, cursor, ptok, pw);
    gemm1_kernel<<<dim3(32, 32, 8), 256, 0, stream>>>(xh, W1, b1, h, cnt, offs, ptok);
    gemm2_kernel<<<dim3(32, 8, 8), 256, 0, stream>>>(h, W2, b2, pw, ptok, cnt, offs, out);
}

// Round 2
// 1172.818 us; speedup vs baseline: 1.1029x; 1.1029x over previous
//
#include <hip/hip_runtime.h>
#include <hip/hip_fp16.h>

// ---- problem constants ----
#define BTOK  4096
#define D_IN  1024
#define D_HID 4096
#define D_OUT 1024
#define NE    8
// TOP_K = 2

typedef _Float16 half8 __attribute__((ext_vector_type(8)));
typedef float    floatx4 __attribute__((ext_vector_type(4)));

// GEMM tiling (m97 structure: 128x128 tile, BK=32, unpadded LDS, global_load_lds w=16)
#define BM 128
#define BN 128
#define BK 32

// ---- ws layout (bytes) ----
// xh  : fp16 x                [4096*1024]   @ 0            (8,388,608)
// Wt  : fp16 W1t/W2t (shared) [8*4096*1024] @ 8,388,608    (67,108,864)
// h   : fp16 hidden           [8192*4096]   @ 75,497,472   (67,108,864)
// t2i : int  top2 idx         [4096*2]      @ 142,606,336  (32,768)
// t2w : f32  top2 weight      [4096*2]      @ 142,639,104  (32,768)
// ptok: int  pair token       [8192]        @ 142,671,872  (32,768)
// pw  : f32  pair weight      [8192]        @ 142,704,640  (32,768)
// meta: cnt[8],cursor[8],offs[8],usage[8]   @ 142,737,408  (128)
// total ~142.7 MB

__device__ __forceinline__ void g2l16(const void* g, void* s) {
    __builtin_amdgcn_global_load_lds((const __attribute__((address_space(1))) void*)g,
                                     (__attribute__((address_space(3))) void*)s, 16, 0, 0);
}

// ---------------- convert x to fp16 ----------------
__global__ void convert_x_kernel(const float* __restrict__ x, _Float16* __restrict__ xh) {
    int i = (blockIdx.x * 256 + threadIdx.x) * 8;
    float4 a = *(const float4*)(x + i);
    float4 b = *(const float4*)(x + i + 4);
    half8 v;
    v[0] = (_Float16)a.x; v[1] = (_Float16)a.y; v[2] = (_Float16)a.z; v[3] = (_Float16)a.w;
    v[4] = (_Float16)b.x; v[5] = (_Float16)b.y; v[6] = (_Float16)b.z; v[7] = (_Float16)b.w;
    *(half8*)(xh + i) = v;
}

// ---------------- convert+transpose W[e][K][N] f32 -> Wt[e][N][K] f16 ----------------
__global__ void transpose_convert_kernel(const float* __restrict__ W, _Float16* __restrict__ Wt,
                                         int K, int N) {
    __shared__ _Float16 t[64][80];   // [n][k], stride 160 B (16B-aligned rows)
    const float* We = W + (size_t)blockIdx.z * K * N;
    _Float16* Wte = Wt + (size_t)blockIdx.z * K * N;
    int k0 = blockIdx.x * 64, n0 = blockIdx.y * 64;
    int tid = threadIdx.x;
    int kr = tid >> 4, nc = (tid & 15) * 4;
    #pragma unroll
    for (int i = 0; i < 4; ++i) {
        int k = kr + i * 16;
        float4 v = *(const float4*)(We + (size_t)(k0 + k) * N + n0 + nc);
        t[nc + 0][k] = (_Float16)v.x;
        t[nc + 1][k] = (_Float16)v.y;
        t[nc + 2][k] = (_Float16)v.z;
        t[nc + 3][k] = (_Float16)v.w;
    }
    __syncthreads();
    #pragma unroll
    for (int it = 0; it < 2; ++it) {
        int task = tid + it * 256;
        int n = task >> 3, kc = (task & 7) * 8;
        half8 v = *(const half8*)&t[n][kc];
        *(half8*)(Wte + (size_t)(n0 + n) * K + k0 + kc) = v;
    }
}

// ---------------- gating: logits (fp64 acc), top-2, softmax, usage ----------------
__global__ void gating_kernel(const float* __restrict__ x, const float* __restrict__ Wg,
                              const float* __restrict__ bg,
                              int* __restrict__ t2i, float* __restrict__ t2w,
                              int* __restrict__ cnt, float* __restrict__ usage) {
    __shared__ float susage[NE];
    int tid = threadIdx.x;
    if (tid < NE) susage[tid] = 0.f;
    __syncthreads();
    int wv = tid >> 6, lane = tid & 63;
    int t = blockIdx.x * 4 + wv;
    double part[NE];
    #pragma unroll
    for (int e = 0; e < NE; ++e) part[e] = 0.0;
    for (int i = lane; i < D_IN; i += 64) {
        double xv = (double)x[(size_t)t * D_IN + i];
        #pragma unroll
        for (int e = 0; e < NE; ++e) part[e] += xv * (double)Wg[i * NE + e];
    }
    #pragma unroll
    for (int e = 0; e < NE; ++e) {
        #pragma unroll
        for (int s = 32; s > 0; s >>= 1) part[e] += __shfl_xor(part[e], s, 64);
    }
    if (lane == 0) {
        float l[NE];
        #pragma unroll
        for (int e = 0; e < NE; ++e) l[e] = (float)part[e] + bg[e];
        float M = l[0];
        #pragma unroll
        for (int e = 1; e < NE; ++e) M = fmaxf(M, l[e]);
        float s = 0.f, g[NE];
        #pragma unroll
        for (int e = 0; e < NE; ++e) { g[e] = __expf(l[e] - M); s += g[e]; }
        float inv = 1.f / s;
        #pragma unroll
        for (int e = 0; e < NE; ++e) atomicAdd(&susage[e], g[e] * inv);
        int i0 = 0; float b0 = l[0];
        #pragma unroll
        for (int e = 1; e < NE; ++e) if (l[e] > b0) { b0 = l[e]; i0 = e; }
        int i1 = -1; float b1v = -1e30f;
        #pragma unroll
        for (int e = 0; e < NE; ++e) if (e != i0 && l[e] > b1v) { b1v = l[e]; i1 = e; }
        float w0 = 1.f / (1.f + expf(b1v - b0));
        t2i[2 * t] = i0; t2i[2 * t + 1] = i1;
        t2w[2 * t] = w0; t2w[2 * t + 1] = 1.f - w0;
        atomicAdd(&cnt[i0], 1);
        atomicAdd(&cnt[i1], 1);
    }
    __syncthreads();
    if (tid < NE) atomicAdd(&usage[tid], susage[tid]);
}

// ---------------- scan + loss ----------------
__global__ void scan_kernel(const int* __restrict__ cnt, int* __restrict__ offs,
                            int* __restrict__ cursor, const float* __restrict__ usage,
                            float* __restrict__ out_loss) {
    if (threadIdx.x == 0) {
        int run = 0;
        for (int e = 0; e < NE; ++e) { offs[e] = run; cursor[e] = run; run += cnt[e]; }
        float loss = 0.f;
        for (int e = 0; e < NE; ++e) { float u = usage[e] / (float)BTOK; loss += u * u; }
        out_loss[0] = (float)NE * loss;
    }
}

// ---------------- scatter pairs into per-expert lists ----------------
__global__ void scatter_kernel(const int* __restrict__ t2i, const float* __restrict__ t2w,
                               int* __restrict__ cursor, int* __restrict__ ptok,
                               float* __restrict__ pw) {
    int t = blockIdx.x * blockDim.x + threadIdx.x;
    if (t >= BTOK) return;
    #pragma unroll
    for (int k = 0; k < 2; ++k) {
        int e = t2i[2 * t + k];
        int slot = atomicAdd(&cursor[e], 1);
        ptok[slot] = t;
        pw[slot] = t2w[2 * t + k];
    }
}

// ---------------- GEMM1: h = relu(xh[tok] @ W1t[e]^T + b1[e]) ----------------
// A: xh rows (gathered), [m][k]; B: W1t [n][k]; both staged via global_load_lds w=16.
__global__ __launch_bounds__(256)
void gemm1_kernel(const _Float16* __restrict__ xh, const _Float16* __restrict__ W1t,
                  const float* __restrict__ b1, _Float16* __restrict__ h,
                  const int* __restrict__ cnt, const int* __restrict__ offs,
                  const int* __restrict__ ptok) {
    int e = blockIdx.z;
    int cnte = cnt[e];
    int row0 = blockIdx.x * BM;
    if (row0 >= cnte) return;
    int n0 = blockIdx.y * BN;
    int off = offs[e];

    __shared__ __align__(16) _Float16 Asm[BM * BK];  // [m][k], 8 KB
    __shared__ __align__(16) _Float16 Bsm[BN * BK];  // [n][k], 8 KB

    int tid = threadIdx.x;
    int wave = tid >> 6, lane = tid & 63;
    int kchunk = (lane & 3) * 8;

    // A/B staging rows for this thread (2 issues each; LDS dest wave-uniform)
    int r0 = wave * 16 + (lane >> 2);
    int r1 = r0 + 64;
    int tok0 = ptok[off + min(row0 + r0, cnte - 1)];
    int tok1 = ptok[off + min(row0 + r1, cnte - 1)];
    const _Float16* aSrc0 = xh + (size_t)tok0 * D_IN + kchunk;
    const _Float16* aSrc1 = xh + (size_t)tok1 * D_IN + kchunk;
    const _Float16* bBase = W1t + (size_t)e * D_IN * D_HID;
    const _Float16* bSrc0 = bBase + (size_t)(n0 + r0) * D_IN + kchunk;
    const _Float16* bSrc1 = bBase + (size_t)(n0 + r1) * D_IN + kchunk;
    _Float16* aDst0 = &Asm[(wave * 16) * BK];
    _Float16* aDst1 = &Asm[(64 + wave * 16) * BK];
    _Float16* bDst0 = &Bsm[(wave * 16) * BK];
    _Float16* bDst1 = &Bsm[(64 + wave * 16) * BK];

    floatx4 acc[4][4] = {};
    int lr = lane & 15, lq = lane >> 4;
    int wm = (wave & 1) * 64, wn = (wave >> 1) * 64;

    for (int k0 = 0; k0 < D_IN; k0 += BK) {
        __syncthreads();
        g2l16(aSrc0 + k0, aDst0);
        g2l16(aSrc1 + k0, aDst1);
        g2l16(bSrc0 + k0, bDst0);
        g2l16(bSrc1 + k0, bDst1);
        __syncthreads();
        half8 af[4], bf[4];
        #pragma unroll
        for (int f = 0; f < 4; ++f) {
            af[f] = *(const half8*)&Asm[(wm + f * 16 + lr) * BK + lq * 8];
            bf[f] = *(const half8*)&Bsm[(wn + f * 16 + lr) * BK + lq * 8];
        }
        #pragma unroll
        for (int mf = 0; mf < 4; ++mf)
            #pragma unroll
            for (int nf = 0; nf < 4; ++nf)
                acc[mf][nf] = __builtin_amdgcn_mfma_f32_16x16x32_f16(af[mf], bf[nf], acc[mf][nf], 0, 0, 0);
    }

    const float* b1e = b1 + (size_t)e * D_HID + n0;
    #pragma unroll
    for (int mf = 0; mf < 4; ++mf) {
        #pragma unroll
        for (int v = 0; v < 4; ++v) {
            int r = wm + mf * 16 + lq * 4 + v;
            int p = row0 + r;
            if (p < cnte) {
                _Float16* hrow = h + (size_t)(off + p) * D_HID + n0;
                #pragma unroll
                for (int nf = 0; nf < 4; ++nf) {
                    int c = wn + nf * 16 + lr;
                    float val = acc[mf][nf][v] + b1e[c];
                    hrow[c] = (_Float16)fmaxf(val, 0.f);
                }
            }
        }
    }
}

// ---------------- GEMM2: out[tok] += w * (h @ W2t[e]^T + b2[e]) ----------------
__global__ __launch_bounds__(256)
void gemm2_kernel(const _Float16* __restrict__ h, const _Float16* __restrict__ W2t,
                  const float* __restrict__ b2, const float* __restrict__ pw,
                  const int* __restrict__ ptok, const int* __restrict__ cnt,
                  const int* __restrict__ offs, float* __restrict__ out) {
    int e = blockIdx.z;
    int cnte = cnt[e];
    int row0 = blockIdx.x * BM;
    if (row0 >= cnte) return;
    int n0 = blockIdx.y * BN;
    int off = offs[e];

    __shared__ __align__(16) _Float16 Asm[BM * BK];
    __shared__ __align__(16) _Float16 Bsm[BN * BK];

    int tid = threadIdx.x;
    int wave = tid >> 6, lane = tid & 63;
    int kchunk = (lane & 3) * 8;

    int r0 = wave * 16 + (lane >> 2);
    int r1 = r0 + 64;
    const _Float16* aSrc0 = h + (size_t)(off + min(row0 + r0, cnte - 1)) * D_HID + kchunk;
    const _Float16* aSrc1 = h + (size_t)(off + min(row0 + r1, cnte - 1)) * D_HID + kchunk;
    const _Float16* bBase = W2t + (size_t)e * D_HID * D_OUT;
    const _Float16* bSrc0 = bBase + (size_t)(n0 + r0) * D_HID + kchunk;
    const _Float16* bSrc1 = bBase + (size_t)(n0 + r1) * D_HID + kchunk;
    _Float16* aDst0 = &Asm[(wave * 16) * BK];
    _Float16* aDst1 = &Asm[(64 + wave * 16) * BK];
    _Float16* bDst0 = &Bsm[(wave * 16) * BK];
    _Float16* bDst1 = &Bsm[(64 + wave * 16) * BK];

    floatx4 acc[4][4] = {};
    int lr = lane & 15, lq = lane >> 4;
    int wm = (wave & 1) * 64, wn = (wave >> 1) * 64;

    for (int k0 = 0; k0 < D_HID; k0 += BK) {
        __syncthreads();
        g2l16(aSrc0 + k0, aDst0);
        g2l16(aSrc1 + k0, aDst1);
        g2l16(bSrc0 + k0, bDst0);
        g2l16(bSrc1 + k0, bDst1);
        __syncthreads();
        half8 af[4], bf[4];
        #pragma unroll
        for (int f = 0; f < 4; ++f) {
            af[f] = *(const half8*)&Asm[(wm + f * 16 + lr) * BK + lq * 8];
            bf[f] = *(const half8*)&Bsm[(wn + f * 16 + lr) * BK + lq * 8];
        }
        #pragma unroll
        for (int mf = 0; mf < 4; ++mf)
            #pragma unroll
            for (int nf = 0; nf < 4; ++nf)
                acc[mf][nf] = __builtin_amdgcn_mfma_f32_16x16x32_f16(af[mf], bf[nf], acc[mf][nf], 0, 0, 0);
    }

    const float* b2e = b2 + (size_t)e * D_OUT + n0;
    #pragma unroll
    for (int mf = 0; mf < 4; ++mf) {
        #pragma unroll
        for (int v = 0; v < 4; ++v) {
            int r = wm + mf * 16 + lq * 4 + v;
            int p = row0 + r;
            if (p < cnte) {
                int tokp = ptok[off + p];
                float wgt = pw[off + p];
                float* orow = out + (size_t)tokp * D_OUT + n0;
                #pragma unroll
                for (int nf = 0; nf < 4; ++nf) {
                    int c = wn + nf * 16 + lr;
                    float val = (acc[mf][nf][v] + b2e[c]) * wgt;
                    atomicAdd(&orow[c], val);
                }
            }
        }
    }
}

extern "C" void kernel_launch(void* const* d_in, const int* in_sizes, int n_in,
                              void* d_out, int out_size, void* d_ws, size_t ws_size,
                              hipStream_t stream) {
    const float* x  = (const float*)d_in[0];
    const float* Wg = (const float*)d_in[1];
    const float* bg = (const float*)d_in[2];
    const float* W1 = (const float*)d_in[3];
    const float* b1 = (const float*)d_in[4];
    const float* W2 = (const float*)d_in[5];
    const float* b2 = (const float*)d_in[6];
    float* out = (float*)d_out;

    char* ws = (char*)d_ws;
    _Float16* xh   = (_Float16*)(ws);
    _Float16* Wt   = (_Float16*)(ws + 8388608ull);     // shared W1t/W2t (67 MB)
    _Float16* h    = (_Float16*)(ws + 75497472ull);
    int*      t2i  = (int*)(ws + 142606336ull);
    float*    t2w  = (float*)(ws + 142639104ull);
    int*      ptok = (int*)(ws + 142671872ull);
    float*    pw   = (float*)(ws + 142704640ull);
    int*      meta = (int*)(ws + 142737408ull);
    int* cnt = meta; int* cursor = meta + 8; int* offs = meta + 16;
    float* usage = (float*)(meta + 24);

    hipMemsetAsync(d_out, 0, ((size_t)BTOK * D_OUT + 1) * sizeof(float), stream);
    hipMemsetAsync(meta, 0, 128, stream);

    convert_x_kernel<<<2048, 256, 0, stream>>>(x, xh);
    gating_kernel<<<1024, 256, 0, stream>>>(x, Wg, bg, t2i, t2w, cnt, usage);
    scan_kernel<<<1, 64, 0, stream>>>(cnt, offs, cursor, usage, out + (size_t)BTOK * D_OUT);
    scatter_kernel<<<16, 256, 0, stream>>>(t2i, t2w, cursor, ptok, pw);

    // W1t = transpose(W1) in fp16, then gemm1; then reuse Wt for W2t, then gemm2.
    transpose_convert_kernel<<<dim3(16, 64, 8), 256, 0, stream>>>(W1, Wt, D_IN, D_HID);
    gemm1_kernel<<<dim3(32, 32, 8), 256, 0, stream>>>(xh, Wt, b1, h, cnt, offs, ptok);
    transpose_convert_kernel<<<dim3(64, 16, 8), 256, 0, stream>>>(W2, Wt, D_HID, D_OUT);
    gemm2_kernel<<<dim3(32, 8, 8), 256, 0, stream>>>(h, Wt, b2, pw, ptok, cnt, offs, out);
}

// Round 3
// 691.725 us; speedup vs baseline: 1.8700x; 1.6955x over previous
//
#include <hip/hip_runtime.h>
#include <hip/hip_fp16.h>

// ---- problem constants ----
#define BTOK  4096
#define D_IN  1024
#define D_HID 4096
#define D_OUT 1024
#define NE    8
#define PT_MAX 72          // max padded pair tiles (8192/128 + 8)
#define P_MAX  9216        // PT_MAX*128
#define HHALF  2048        // hidden split
#define KT1    32          // gemm1 K-chunks (1024/32)
#define NT1    16          // gemm1 N-tiles per half (2048/128)
#define KT2    64          // gemm2 K-chunks per half (2048/32)
#define NT2    8           // gemm2 N-tiles (1024/128)

typedef _Float16 half8 __attribute__((ext_vector_type(8)));
typedef _Float16 half4v __attribute__((ext_vector_type(4)));
typedef float    floatx4 __attribute__((ext_vector_type(4)));

// ---- ws layout (bytes) ----
// xt   : f16 x tiles   [72][32][128x32]   @ 0            (18,874,368)
// Wt   : f16 W tiles (reused 4x)          @ 18,874,368   (33,554,432)
// ht   : f16 h tiles   [72][64][128x32]   @ 52,428,800   (37,748,736)
// yA   : f16 y half A  [9216][1024]       @ 90,177,536   (18,874,368)
// yB   : f16 y half B  [9216][1024]       @ 109,051,904  (18,874,368)
// t2i  : int [8192]                       @ 127,926,272  (32,768)
// t2w  : f32 [8192]                       @ 127,959,040  (32,768)
// ptok : int [9216]                       @ 127,991,808  (36,864)
// pslot: int [8192]                       @ 128,028,672  (32,768)
// meta : ints cnt8,cur8,offs8,tile2e72,ntiles,usage f32  @ 128,061,440 (512)
// total ~128.1 MB

__device__ __forceinline__ void g2l16(const void* g, void* s) {
    __builtin_amdgcn_global_load_lds((const __attribute__((address_space(1))) void*)g,
                                     (__attribute__((address_space(3))) void*)s, 16, 0, 0);
}

// ---------------- gating: logits (fp64 acc), top-2, softmax, usage ----------------
__global__ void gating_kernel(const float* __restrict__ x, const float* __restrict__ Wg,
                              const float* __restrict__ bg,
                              int* __restrict__ t2i, float* __restrict__ t2w,
                              int* __restrict__ cnt, float* __restrict__ usage) {
    __shared__ float susage[NE];
    int tid = threadIdx.x;
    if (tid < NE) susage[tid] = 0.f;
    __syncthreads();
    int wv = tid >> 6, lane = tid & 63;
    int t = blockIdx.x * 4 + wv;
    double part[NE];
    #pragma unroll
    for (int e = 0; e < NE; ++e) part[e] = 0.0;
    for (int i = lane; i < D_IN; i += 64) {
        double xv = (double)x[(size_t)t * D_IN + i];
        #pragma unroll
        for (int e = 0; e < NE; ++e) part[e] += xv * (double)Wg[i * NE + e];
    }
    #pragma unroll
    for (int e = 0; e < NE; ++e) {
        #pragma unroll
        for (int s = 32; s > 0; s >>= 1) part[e] += __shfl_xor(part[e], s, 64);
    }
    if (lane == 0) {
        float l[NE];
        #pragma unroll
        for (int e = 0; e < NE; ++e) l[e] = (float)part[e] + bg[e];
        float M = l[0];
        #pragma unroll
        for (int e = 1; e < NE; ++e) M = fmaxf(M, l[e]);
        float s = 0.f, g[NE];
        #pragma unroll
        for (int e = 0; e < NE; ++e) { g[e] = __expf(l[e] - M); s += g[e]; }
        float inv = 1.f / s;
        #pragma unroll
        for (int e = 0; e < NE; ++e) atomicAdd(&susage[e], g[e] * inv);
        int i0 = 0; float b0 = l[0];
        #pragma unroll
        for (int e = 1; e < NE; ++e) if (l[e] > b0) { b0 = l[e]; i0 = e; }
        int i1 = -1; float b1v = -1e30f;
        #pragma unroll
        for (int e = 0; e < NE; ++e) if (e != i0 && l[e] > b1v) { b1v = l[e]; i1 = e; }
        float w0 = 1.f / (1.f + expf(b1v - b0));
        t2i[2 * t] = i0; t2i[2 * t + 1] = i1;
        t2w[2 * t] = w0; t2w[2 * t + 1] = 1.f - w0;
        atomicAdd(&cnt[i0], 1);
        atomicAdd(&cnt[i1], 1);
    }
    __syncthreads();
    if (tid < NE) atomicAdd(&usage[tid], susage[tid]);
}

// ---------------- scan: padded offsets, tile->expert map, loss ----------------
__global__ void scan_kernel(int* __restrict__ meta, float* __restrict__ out_loss) {
    if (threadIdx.x != 0) return;
    int* cnt = meta; int* cursor = meta + 8; int* offs = meta + 16;
    int* tile2e = meta + 24; int* ntiles = meta + 96;
    float* usage = (float*)(meta + 100);
    int run = 0;
    for (int e = 0; e < NE; ++e) {
        offs[e] = run; cursor[e] = run;
        int ntl = (cnt[e] + 127) >> 7;
        int t0 = run >> 7;
        for (int i = 0; i < ntl; ++i) tile2e[t0 + i] = e;
        run += ntl << 7;
    }
    ntiles[0] = run >> 7;
    float loss = 0.f;
    for (int e = 0; e < NE; ++e) { float u = usage[e] / (float)BTOK; loss += u * u; }
    out_loss[0] = (float)NE * loss;
}

// ---------------- fill padded slots with token 0 ----------------
__global__ void fill_kernel(int* __restrict__ ptok) {
    ptok[blockIdx.x * 256 + threadIdx.x] = 0;
}

// ---------------- scatter pairs into padded per-expert lists ----------------
__global__ void scatter_kernel(const int* __restrict__ t2i, int* __restrict__ cursor,
                               int* __restrict__ ptok, int* __restrict__ pslot) {
    int t = blockIdx.x * blockDim.x + threadIdx.x;
    if (t >= BTOK) return;
    #pragma unroll
    for (int k = 0; k < 2; ++k) {
        int e = t2i[2 * t + k];
        int slot = atomicAdd(&cursor[e], 1);
        ptok[slot] = t;
        pslot[2 * t + k] = slot;
    }
}

// ---------------- gather x into tiled fp16 [ptile][k0][128x32] ----------------
__global__ void gather_x_kernel(const float* __restrict__ x, const int* __restrict__ ptok,
                                _Float16* __restrict__ xt) {
    int k0 = blockIdx.x, ptile = blockIdx.y;
    int t = threadIdx.x;
    int m = t >> 1, kb = (t & 1) * 16;
    int tok = ptok[ptile * 128 + m];
    const float* src = x + (size_t)tok * D_IN + k0 * 32 + kb;
    float4 v0 = *(const float4*)(src);
    float4 v1 = *(const float4*)(src + 4);
    float4 v2 = *(const float4*)(src + 8);
    float4 v3 = *(const float4*)(src + 12);
    half8 o0, o1;
    o0[0]=(_Float16)v0.x; o0[1]=(_Float16)v0.y; o0[2]=(_Float16)v0.z; o0[3]=(_Float16)v0.w;
    o0[4]=(_Float16)v1.x; o0[5]=(_Float16)v1.y; o0[6]=(_Float16)v1.z; o0[7]=(_Float16)v1.w;
    o1[0]=(_Float16)v2.x; o1[1]=(_Float16)v2.y; o1[2]=(_Float16)v2.z; o1[3]=(_Float16)v2.w;
    o1[4]=(_Float16)v3.x; o1[5]=(_Float16)v3.y; o1[6]=(_Float16)v3.z; o1[7]=(_Float16)v3.w;
    _Float16* dst = xt + ((size_t)ptile * KT1 + k0) * 4096 + t * 16;
    *(half8*)dst = o0;
    *(half8*)(dst + 8) = o1;
}

// ---------------- W [e][Ktot][Ntot] f32 -> tiles [e][nt][k0][128x32] f16 ----------------
__global__ void wtile_kernel(const float* __restrict__ W, _Float16* __restrict__ Wt,
                             int Ktot, int Ntot, int k_off, int n_off, int KT, int NT) {
    int k0 = blockIdx.x, ntb = blockIdx.y, e = blockIdx.z;
    int t = threadIdx.x;
    int nl = t >> 1, kb = (t & 1) * 16;
    const float* src = W + ((size_t)e * Ktot + k_off + k0 * 32 + kb) * Ntot
                         + n_off + ntb * 128 + nl;
    float v[16];
    #pragma unroll
    for (int j = 0; j < 16; ++j) v[j] = src[(size_t)j * Ntot];
    half8 o0, o1;
    #pragma unroll
    for (int j = 0; j < 8; ++j) { o0[j] = (_Float16)v[j]; o1[j] = (_Float16)v[j + 8]; }
    _Float16* dst = Wt + (((size_t)e * NT + ntb) * KT + k0) * 4096 + t * 16;
    *(half8*)dst = o0;
    *(half8*)(dst + 8) = o1;
}

// ---------------- GEMM1: ht-tiles = relu(xt @ W1t^T + b1) ----------------
__global__ __launch_bounds__(256)
void gemm1_kernel(const _Float16* __restrict__ xt, const _Float16* __restrict__ W1t,
                  const float* __restrict__ b1, _Float16* __restrict__ ht,
                  const int* __restrict__ meta, int n_off) {
    int ptile = blockIdx.x;
    if (ptile >= meta[96]) return;
    int nt = blockIdx.y;
    int e = meta[24 + ptile];

    __shared__ __align__(16) _Float16 Asm[128 * 32];
    __shared__ __align__(16) _Float16 Bsm[128 * 32];

    int tid = threadIdx.x;
    int wave = tid >> 6, lane = tid & 63;
    const _Float16* Abase = xt + (size_t)ptile * KT1 * 4096;
    const _Float16* Bbase = W1t + ((size_t)(e * NT1 + nt) * KT1) * 4096;
    int stg = wave * 512 + lane * 8;

    floatx4 acc[4][4] = {};
    int lr = lane & 15, lq = lane >> 4;
    int wm = (wave & 1) * 64, wn = (wave >> 1) * 64;

    for (int k0 = 0; k0 < KT1; ++k0) {
        __syncthreads();
        const _Float16* aG = Abase + (size_t)k0 * 4096 + stg;
        const _Float16* bG = Bbase + (size_t)k0 * 4096 + stg;
        g2l16(aG,        &Asm[wave * 512]);
        g2l16(aG + 2048, &Asm[wave * 512 + 2048]);
        g2l16(bG,        &Bsm[wave * 512]);
        g2l16(bG + 2048, &Bsm[wave * 512 + 2048]);
        __syncthreads();
        half8 af[4], bf[4];
        #pragma unroll
        for (int f = 0; f < 4; ++f) {
            af[f] = *(const half8*)&Asm[(wm + f * 16 + lr) * 32 + lq * 8];
            bf[f] = *(const half8*)&Bsm[(wn + f * 16 + lr) * 32 + lq * 8];
        }
        #pragma unroll
        for (int mf = 0; mf < 4; ++mf)
            #pragma unroll
            for (int nf = 0; nf < 4; ++nf)
                acc[mf][nf] = __builtin_amdgcn_mfma_f32_16x16x32_f16(af[mf], bf[nf], acc[mf][nf], 0, 0, 0);
    }

    const float* b1e = b1 + (size_t)e * D_HID + n_off;
    #pragma unroll
    for (int mf = 0; mf < 4; ++mf) {
        #pragma unroll
        for (int v = 0; v < 4; ++v) {
            int m = wm + mf * 16 + lq * 4 + v;
            #pragma unroll
            for (int nf = 0; nf < 4; ++nf) {
                int hl = nt * 128 + wn + nf * 16 + lr;
                float val = acc[mf][nf][v] + b1e[hl];
                ht[((size_t)ptile * KT2 + (hl >> 5)) * 4096 + m * 32 + (hl & 31)]
                    = (_Float16)fmaxf(val, 0.f);
            }
        }
    }
}

// ---------------- GEMM2: y = ht @ W2t^T (raw, fp16) ----------------
__global__ __launch_bounds__(256)
void gemm2_kernel(const _Float16* __restrict__ ht, const _Float16* __restrict__ W2t,
                  _Float16* __restrict__ y, const int* __restrict__ meta) {
    int ptile = blockIdx.x;
    if (ptile >= meta[96]) return;
    int nt = blockIdx.y;
    int e = meta[24 + ptile];

    __shared__ __align__(16) _Float16 Asm[128 * 32];
    __shared__ __align__(16) _Float16 Bsm[128 * 32];

    int tid = threadIdx.x;
    int wave = tid >> 6, lane = tid & 63;
    const _Float16* Abase = ht + (size_t)ptile * KT2 * 4096;
    const _Float16* Bbase = W2t + ((size_t)(e * NT2 + nt) * KT2) * 4096;
    int stg = wave * 512 + lane * 8;

    floatx4 acc[4][4] = {};
    int lr = lane & 15, lq = lane >> 4;
    int wm = (wave & 1) * 64, wn = (wave >> 1) * 64;

    for (int k0 = 0; k0 < KT2; ++k0) {
        __syncthreads();
        const _Float16* aG = Abase + (size_t)k0 * 4096 + stg;
        const _Float16* bG = Bbase + (size_t)k0 * 4096 + stg;
        g2l16(aG,        &Asm[wave * 512]);
        g2l16(aG + 2048, &Asm[wave * 512 + 2048]);
        g2l16(bG,        &Bsm[wave * 512]);
        g2l16(bG + 2048, &Bsm[wave * 512 + 2048]);
        __syncthreads();
        half8 af[4], bf[4];
        #pragma unroll
        for (int f = 0; f < 4; ++f) {
            af[f] = *(const half8*)&Asm[(wm + f * 16 + lr) * 32 + lq * 8];
            bf[f] = *(const half8*)&Bsm[(wn + f * 16 + lr) * 32 + lq * 8];
        }
        #pragma unroll
        for (int mf = 0; mf < 4; ++mf)
            #pragma unroll
            for (int nf = 0; nf < 4; ++nf)
                acc[mf][nf] = __builtin_amdgcn_mfma_f32_16x16x32_f16(af[mf], bf[nf], acc[mf][nf], 0, 0, 0);
    }

    #pragma unroll
    for (int mf = 0; mf < 4; ++mf) {
        #pragma unroll
        for (int v = 0; v < 4; ++v) {
            int m = wm + mf * 16 + lq * 4 + v;
            #pragma unroll
            for (int nf = 0; nf < 4; ++nf) {
                int c = nt * 128 + wn + nf * 16 + lr;
                y[(size_t)(ptile * 128 + m) * D_OUT + c] = (_Float16)acc[mf][nf][v];
            }
        }
    }
}

// ---------------- combine: out[t] = sum_k w_k * (yA+yB + b2[e_k]) ----------------
__global__ void combine_kernel(const _Float16* __restrict__ yA, const _Float16* __restrict__ yB,
                               const float* __restrict__ b2, const int* __restrict__ t2i,
                               const float* __restrict__ t2w, const int* __restrict__ pslot,
                               float* __restrict__ out) {
    int t = blockIdx.x;
    int c = threadIdx.x * 4;
    int e0 = t2i[2 * t], e1 = t2i[2 * t + 1];
    float w0 = t2w[2 * t], w1 = t2w[2 * t + 1];
    size_t s0 = (size_t)pslot[2 * t] * D_OUT + c;
    size_t s1 = (size_t)pslot[2 * t + 1] * D_OUT + c;
    half4v a0 = *(const half4v*)(yA + s0);
    half4v b0 = *(const half4v*)(yB + s0);
    half4v a1 = *(const half4v*)(yA + s1);
    half4v b1v = *(const half4v*)(yB + s1);
    float4 bias0 = *(const float4*)(b2 + (size_t)e0 * D_OUT + c);
    float4 bias1 = *(const float4*)(b2 + (size_t)e1 * D_OUT + c);
    float4 o;
    o.x = w0 * ((float)a0[0] + (float)b0[0] + bias0.x) + w1 * ((float)a1[0] + (float)b1v[0] + bias1.x);
    o.y = w0 * ((float)a0[1] + (float)b0[1] + bias0.y) + w1 * ((float)a1[1] + (float)b1v[1] + bias1.y);
    o.z = w0 * ((float)a0[2] + (float)b0[2] + bias0.z) + w1 * ((float)a1[2] + (float)b1v[2] + bias1.z);
    o.w = w0 * ((float)a0[3] + (float)b0[3] + bias0.w) + w1 * ((float)a1[3] + (float)b1v[3] + bias1.w);
    *(float4*)(out + (size_t)t * D_OUT + c) = o;
}

extern "C" void kernel_launch(void* const* d_in, const int* in_sizes, int n_in,
                              void* d_out, int out_size, void* d_ws, size_t ws_size,
                              hipStream_t stream) {
    const float* x  = (const float*)d_in[0];
    const float* Wg = (const float*)d_in[1];
    const float* bg = (const float*)d_in[2];
    const float* W1 = (const float*)d_in[3];
    const float* b1 = (const float*)d_in[4];
    const float* W2 = (const float*)d_in[5];
    const float* b2 = (const float*)d_in[6];
    float* out = (float*)d_out;

    char* ws = (char*)d_ws;
    _Float16* xt    = (_Float16*)(ws);
    _Float16* Wt    = (_Float16*)(ws + 18874368ull);
    _Float16* ht    = (_Float16*)(ws + 52428800ull);
    _Float16* yA    = (_Float16*)(ws + 90177536ull);
    _Float16* yB    = (_Float16*)(ws + 109051904ull);
    int*      t2i   = (int*)(ws + 127926272ull);
    float*    t2w   = (float*)(ws + 127959040ull);
    int*      ptok  = (int*)(ws + 127991808ull);
    int*      pslot = (int*)(ws + 128028672ull);
    int*      meta  = (int*)(ws + 128061440ull);
    int* cnt = meta; int* cursor = meta + 8;
    float* usage = (float*)(meta + 100);

    hipMemsetAsync(meta, 0, 512, stream);

    gating_kernel<<<1024, 256, 0, stream>>>(x, Wg, bg, t2i, t2w, cnt, usage);
    scan_kernel<<<1, 64, 0, stream>>>(meta, out + (size_t)BTOK * D_OUT);
    fill_kernel<<<36, 256, 0, stream>>>(ptok);
    scatter_kernel<<<16, 256, 0, stream>>>(t2i, cursor, ptok, pslot);
    gather_x_kernel<<<dim3(KT1, PT_MAX), 256, 0, stream>>>(x, ptok, xt);

    // half A: hidden [0, 2048)
    wtile_kernel<<<dim3(KT1, NT1, 8), 256, 0, stream>>>(W1, Wt, D_IN, D_HID, 0, 0, KT1, NT1);
    gemm1_kernel<<<dim3(PT_MAX, NT1), 256, 0, stream>>>(xt, Wt, b1, ht, meta, 0);
    wtile_kernel<<<dim3(KT2, NT2, 8), 256, 0, stream>>>(W2, Wt, D_HID, D_OUT, 0, 0, KT2, NT2);
    gemm2_kernel<<<dim3(PT_MAX, NT2), 256, 0, stream>>>(ht, Wt, yA, meta);

    // half B: hidden [2048, 4096)
    wtile_kernel<<<dim3(KT1, NT1, 8), 256, 0, stream>>>(W1, Wt, D_IN, D_HID, 0, HHALF, KT1, NT1);
    gemm1_kernel<<<dim3(PT_MAX, NT1), 256, 0, stream>>>(xt, Wt, b1, ht, meta, HHALF);
    wtile_kernel<<<dim3(KT2, NT2, 8), 256, 0, stream>>>(W2, Wt, D_HID, D_OUT, HHALF, 0, KT2, NT2);
    gemm2_kernel<<<dim3(PT_MAX, NT2), 256, 0, stream>>>(ht, Wt, yB, meta);

    combine_kernel<<<BTOK, 256, 0, stream>>>(yA, yB, b2, t2i, t2w, pslot, out);
}

// Round 4
// 575.395 us; speedup vs baseline: 2.2481x; 1.2022x over previous
//
#include <hip/hip_runtime.h>
#include <hip/hip_fp16.h>

// ---- problem constants ----
#define BTOK  4096
#define D_IN  1024
#define D_HID 4096
#define D_OUT 1024
#define NE    8
#define PT_MAX 72          // max padded pair tiles (8192/128 + 8)
#define P_MAX  9216        // PT_MAX*128
#define HHALF  2048        // hidden split
#define KT1    32          // gemm1 K-chunks (1024/32)
#define NT1    16          // gemm1 N-tiles per half (2048/128)
#define KT2    64          // gemm2 K-chunks per half (2048/32)
#define NT2    8           // gemm2 N-tiles (1024/128)
#define GB     256         // gating blocks

typedef _Float16 half8 __attribute__((ext_vector_type(8)));
typedef _Float16 half4v __attribute__((ext_vector_type(4)));
typedef float    floatx4 __attribute__((ext_vector_type(4)));

// ---- ws layout (bytes) ----
// xt   : f16 x tiles   [72][32][128x32]   @ 0            (18,874,368)
// Wt   : f16 W tiles (reused 4x)          @ 18,874,368   (33,554,432)
// ht   : f16 h tiles   [72][64][128x32]   @ 52,428,800   (37,748,736)
// yA   : f16 y half A  [9216][1024]       @ 90,177,536   (18,874,368)
// yB   : f16 y half B  [9216][1024]       @ 109,051,904  (18,874,368)
// t2i  : int [8192]                       @ 127,926,272  (32,768)
// t2w  : f32 [8192]                       @ 127,959,040  (32,768)
// ptok : int [9216]                       @ 127,991,808  (36,864)
// pslot: int [8192]                       @ 128,028,672  (32,768)
// meta : cnt8,cur8,offs8,tile2e72,ntiles  @ 128,061,440  (512)
// pcnt : int  [256*8]                     @ 128,061,952  (8,192)
// pusage: f32 [256*8]                     @ 128,070,144  (8,192)
// total ~128.1 MB

__device__ __forceinline__ void g2l16(const void* g, void* s) {
    __builtin_amdgcn_global_load_lds((const __attribute__((address_space(1))) void*)g,
                                     (__attribute__((address_space(3))) void*)s, 16, 0, 0);
}

// ---------------- gating: fp64 logits, top-2, softmax; LDS-aggregated partials ----------------
__global__ __launch_bounds__(256)
void gating_kernel(const float* __restrict__ x, const float* __restrict__ Wg,
                   const float* __restrict__ bg,
                   int* __restrict__ t2i, float* __restrict__ t2w,
                   int* __restrict__ pcnt, float* __restrict__ pusage) {
    __shared__ float wgT[NE * 1024];   // transposed gate weights: [e][i]
    __shared__ float susage[NE];
    __shared__ int   scnt[NE];
    int tid = threadIdx.x;
    if (tid < NE) { susage[tid] = 0.f; scnt[tid] = 0; }
    #pragma unroll
    for (int k = 0; k < 8192; k += 256) {
        int idx = k + tid;
        wgT[(idx & 7) * 1024 + (idx >> 3)] = Wg[idx];
    }
    __syncthreads();
    int wv = tid >> 6, lane = tid & 63;
    for (int tt = 0; tt < 4; ++tt) {
        int t = blockIdx.x * 16 + wv * 4 + tt;
        double part[NE];
        #pragma unroll
        for (int e = 0; e < NE; ++e) part[e] = 0.0;
        #pragma unroll
        for (int j = 0; j < 16; ++j) {
            int i = j * 64 + lane;
            double xv = (double)x[(size_t)t * D_IN + i];
            #pragma unroll
            for (int e = 0; e < NE; ++e) part[e] += xv * (double)wgT[e * 1024 + i];
        }
        #pragma unroll
        for (int e = 0; e < NE; ++e) {
            #pragma unroll
            for (int s = 32; s > 0; s >>= 1) part[e] += __shfl_xor(part[e], s, 64);
        }
        if (lane == 0) {
            float l[NE];
            #pragma unroll
            for (int e = 0; e < NE; ++e) l[e] = (float)part[e] + bg[e];
            float M = l[0];
            #pragma unroll
            for (int e = 1; e < NE; ++e) M = fmaxf(M, l[e]);
            float s = 0.f, g[NE];
            #pragma unroll
            for (int e = 0; e < NE; ++e) { g[e] = __expf(l[e] - M); s += g[e]; }
            float inv = 1.f / s;
            #pragma unroll
            for (int e = 0; e < NE; ++e) atomicAdd(&susage[e], g[e] * inv);
            int i0 = 0; float b0 = l[0];
            #pragma unroll
            for (int e = 1; e < NE; ++e) if (l[e] > b0) { b0 = l[e]; i0 = e; }
            int i1 = -1; float b1v = -1e30f;
            #pragma unroll
            for (int e = 0; e < NE; ++e) if (e != i0 && l[e] > b1v) { b1v = l[e]; i1 = e; }
            float w0 = 1.f / (1.f + expf(b1v - b0));
            t2i[2 * t] = i0; t2i[2 * t + 1] = i1;
            t2w[2 * t] = w0; t2w[2 * t + 1] = 1.f - w0;
            atomicAdd(&scnt[i0], 1);
            atomicAdd(&scnt[i1], 1);
        }
    }
    __syncthreads();
    if (tid < NE) {
        pcnt[blockIdx.x * NE + tid] = scnt[tid];
        pusage[blockIdx.x * NE + tid] = susage[tid];
    }
}

// ---------------- scan: reduce partials, padded offsets, tile->expert map, loss ----------------
__global__ void scan_kernel(const int* __restrict__ pcnt, const float* __restrict__ pusage,
                            int* __restrict__ meta, float* __restrict__ out_loss) {
    int lane = threadIdx.x;           // 64 threads
    int e = lane & 7, b0 = lane >> 3;
    int c = 0; float u = 0.f;
    for (int b = b0; b < GB; b += 8) { c += pcnt[b * 8 + e]; u += pusage[b * 8 + e]; }
    #pragma unroll
    for (int s = 8; s < 64; s <<= 1) { c += __shfl_xor(c, s, 64); u += __shfl_xor(u, s, 64); }
    int cAll[NE]; float uAll[NE];
    #pragma unroll
    for (int q = 0; q < NE; ++q) { cAll[q] = __shfl(c, q, 64); uAll[q] = __shfl(u, q, 64); }
    if (lane == 0) {
        int* cnt = meta; int* cursor = meta + 8; int* offs = meta + 16;
        int* tile2e = meta + 24; int* ntiles = meta + 96;
        int run = 0;
        for (int q = 0; q < NE; ++q) {
            cnt[q] = cAll[q];
            offs[q] = run; cursor[q] = run;
            int ntl = (cAll[q] + 127) >> 7;
            int tb = run >> 7;
            for (int i = 0; i < ntl; ++i) tile2e[tb + i] = q;
            run += ntl << 7;
        }
        ntiles[0] = run >> 7;
        float loss = 0.f;
        for (int q = 0; q < NE; ++q) { float uu = uAll[q] / (float)BTOK; loss += uu * uu; }
        out_loss[0] = (float)NE * loss;
    }
}

// ---------------- fill padded slots with token 0 ----------------
__global__ void fill_kernel(int* __restrict__ ptok) {
    ptok[blockIdx.x * 256 + threadIdx.x] = 0;
}

// ---------------- scatter: LDS-aggregated slot assignment ----------------
__global__ void scatter_kernel(const int* __restrict__ t2i, int* __restrict__ cursor,
                               int* __restrict__ ptok, int* __restrict__ pslot) {
    __shared__ int lcnt[NE], base[NE];
    int tid = threadIdx.x;
    if (tid < NE) lcnt[tid] = 0;
    __syncthreads();
    int t = blockIdx.x * 256 + tid;
    int e0 = t2i[2 * t], e1 = t2i[2 * t + 1];
    int l0 = atomicAdd(&lcnt[e0], 1);
    int l1 = atomicAdd(&lcnt[e1], 1);
    __syncthreads();
    if (tid < NE) base[tid] = atomicAdd(&cursor[tid], lcnt[tid]);
    __syncthreads();
    int s0 = base[e0] + l0, s1 = base[e1] + l1;
    ptok[s0] = t; ptok[s1] = t;
    pslot[2 * t] = s0; pslot[2 * t + 1] = s1;
}

// ---------------- gather x into tiled fp16 [ptile][k0][128x32] ----------------
__global__ void gather_x_kernel(const float* __restrict__ x, const int* __restrict__ ptok,
                                _Float16* __restrict__ xt) {
    int k0 = blockIdx.x, ptile = blockIdx.y;
    int t = threadIdx.x;
    int m = t >> 1, kb = (t & 1) * 16;
    int tok = ptok[ptile * 128 + m];
    const float* src = x + (size_t)tok * D_IN + k0 * 32 + kb;
    float4 v0 = *(const float4*)(src);
    float4 v1 = *(const float4*)(src + 4);
    float4 v2 = *(const float4*)(src + 8);
    float4 v3 = *(const float4*)(src + 12);
    half8 o0, o1;
    o0[0]=(_Float16)v0.x; o0[1]=(_Float16)v0.y; o0[2]=(_Float16)v0.z; o0[3]=(_Float16)v0.w;
    o0[4]=(_Float16)v1.x; o0[5]=(_Float16)v1.y; o0[6]=(_Float16)v1.z; o0[7]=(_Float16)v1.w;
    o1[0]=(_Float16)v2.x; o1[1]=(_Float16)v2.y; o1[2]=(_Float16)v2.z; o1[3]=(_Float16)v2.w;
    o1[4]=(_Float16)v3.x; o1[5]=(_Float16)v3.y; o1[6]=(_Float16)v3.z; o1[7]=(_Float16)v3.w;
    _Float16* dst = xt + ((size_t)ptile * KT1 + k0) * 4096 + t * 16;
    *(half8*)dst = o0;
    *(half8*)(dst + 8) = o1;
}

// ---------------- W [e][Ktot][Ntot] f32 -> tiles [e][nt][k0][128x32] f16 ----------------
__global__ void wtile_kernel(const float* __restrict__ W, _Float16* __restrict__ Wt,
                             int Ktot, int Ntot, int k_off, int n_off, int KT, int NT) {
    int k0 = blockIdx.x, ntb = blockIdx.y, e = blockIdx.z;
    int t = threadIdx.x;
    int nl = t >> 1, kb = (t & 1) * 16;
    const float* src = W + ((size_t)e * Ktot + k_off + k0 * 32 + kb) * Ntot
                         + n_off + ntb * 128 + nl;
    float v[16];
    #pragma unroll
    for (int j = 0; j < 16; ++j) v[j] = src[(size_t)j * Ntot];
    half8 o0, o1;
    #pragma unroll
    for (int j = 0; j < 8; ++j) { o0[j] = (_Float16)v[j]; o1[j] = (_Float16)v[j + 8]; }
    _Float16* dst = Wt + (((size_t)e * NT + ntb) * KT + k0) * 4096 + t * 16;
    *(half8*)dst = o0;
    *(half8*)(dst + 8) = o1;
}

// ---------------- GEMM1: ht-tiles = relu(xt @ W1t^T + b1) ----------------
__global__ __launch_bounds__(256)
void gemm1_kernel(const _Float16* __restrict__ xt, const _Float16* __restrict__ W1t,
                  const float* __restrict__ b1, _Float16* __restrict__ ht,
                  const int* __restrict__ meta, int n_off) {
    int ptile = blockIdx.x;
    if (ptile >= meta[96]) return;
    int nt = blockIdx.y;
    int e = meta[24 + ptile];

    __shared__ __align__(16) _Float16 Asm[128 * 32];
    __shared__ __align__(16) _Float16 Bsm[128 * 32];

    int tid = threadIdx.x;
    int wave = tid >> 6, lane = tid & 63;
    const _Float16* Abase = xt + (size_t)ptile * KT1 * 4096;
    const _Float16* Bbase = W1t + ((size_t)(e * NT1 + nt) * KT1) * 4096;
    int stg = wave * 512 + lane * 8;

    floatx4 acc[4][4] = {};
    int lr = lane & 15, lq = lane >> 4;
    int wm = (wave & 1) * 64, wn = (wave >> 1) * 64;

    for (int k0 = 0; k0 < KT1; ++k0) {
        __syncthreads();
        const _Float16* aG = Abase + (size_t)k0 * 4096 + stg;
        const _Float16* bG = Bbase + (size_t)k0 * 4096 + stg;
        g2l16(aG,        &Asm[wave * 512]);
        g2l16(aG + 2048, &Asm[wave * 512 + 2048]);
        g2l16(bG,        &Bsm[wave * 512]);
        g2l16(bG + 2048, &Bsm[wave * 512 + 2048]);
        __syncthreads();
        half8 af[4], bf[4];
        #pragma unroll
        for (int f = 0; f < 4; ++f) {
            af[f] = *(const half8*)&Asm[(wm + f * 16 + lr) * 32 + lq * 8];
            bf[f] = *(const half8*)&Bsm[(wn + f * 16 + lr) * 32 + lq * 8];
        }
        #pragma unroll
        for (int mf = 0; mf < 4; ++mf)
            #pragma unroll
            for (int nf = 0; nf < 4; ++nf)
                acc[mf][nf] = __builtin_amdgcn_mfma_f32_16x16x32_f16(af[mf], bf[nf], acc[mf][nf], 0, 0, 0);
    }

    const float* b1e = b1 + (size_t)e * D_HID + n_off;
    #pragma unroll
    for (int mf = 0; mf < 4; ++mf) {
        #pragma unroll
        for (int v = 0; v < 4; ++v) {
            int m = wm + mf * 16 + lq * 4 + v;
            #pragma unroll
            for (int nf = 0; nf < 4; ++nf) {
                int hl = nt * 128 + wn + nf * 16 + lr;
                float val = acc[mf][nf][v] + b1e[hl];
                ht[((size_t)ptile * KT2 + (hl >> 5)) * 4096 + m * 32 + (hl & 31)]
                    = (_Float16)fmaxf(val, 0.f);
            }
        }
    }
}

// ---------------- GEMM2: y = ht @ W2t^T (raw, fp16) ----------------
__global__ __launch_bounds__(256)
void gemm2_kernel(const _Float16* __restrict__ ht, const _Float16* __restrict__ W2t,
                  _Float16* __restrict__ y, const int* __restrict__ meta) {
    int ptile = blockIdx.x;
    if (ptile >= meta[96]) return;
    int nt = blockIdx.y;
    int e = meta[24 + ptile];

    __shared__ __align__(16) _Float16 Asm[128 * 32];
    __shared__ __align__(16) _Float16 Bsm[128 * 32];

    int tid = threadIdx.x;
    int wave = tid >> 6, lane = tid & 63;
    const _Float16* Abase = ht + (size_t)ptile * KT2 * 4096;
    const _Float16* Bbase = W2t + ((size_t)(e * NT2 + nt) * KT2) * 4096;
    int stg = wave * 512 + lane * 8;

    floatx4 acc[4][4] = {};
    int lr = lane & 15, lq = lane >> 4;
    int wm = (wave & 1) * 64, wn = (wave >> 1) * 64;

    for (int k0 = 0; k0 < KT2; ++k0) {
        __syncthreads();
        const _Float16* aG = Abase + (size_t)k0 * 4096 + stg;
        const _Float16* bG = Bbase + (size_t)k0 * 4096 + stg;
        g2l16(aG,        &Asm[wave * 512]);
        g2l16(aG + 2048, &Asm[wave * 512 + 2048]);
        g2l16(bG,        &Bsm[wave * 512]);
        g2l16(bG + 2048, &Bsm[wave * 512 + 2048]);
        __syncthreads();
        half8 af[4], bf[4];
        #pragma unroll
        for (int f = 0; f < 4; ++f) {
            af[f] = *(const half8*)&Asm[(wm + f * 16 + lr) * 32 + lq * 8];
            bf[f] = *(const half8*)&Bsm[(wn + f * 16 + lr) * 32 + lq * 8];
        }
        #pragma unroll
        for (int mf = 0; mf < 4; ++mf)
            #pragma unroll
            for (int nf = 0; nf < 4; ++nf)
                acc[mf][nf] = __builtin_amdgcn_mfma_f32_16x16x32_f16(af[mf], bf[nf], acc[mf][nf], 0, 0, 0);
    }

    #pragma unroll
    for (int mf = 0; mf < 4; ++mf) {
        #pragma unroll
        for (int v = 0; v < 4; ++v) {
            int m = wm + mf * 16 + lq * 4 + v;
            #pragma unroll
            for (int nf = 0; nf < 4; ++nf) {
                int c = nt * 128 + wn + nf * 16 + lr;
                y[(size_t)(ptile * 128 + m) * D_OUT + c] = (_Float16)acc[mf][nf][v];
            }
        }
    }
}

// ---------------- combine: out[t] = sum_k w_k * (yA+yB + b2[e_k]) ----------------
__global__ void combine_kernel(const _Float16* __restrict__ yA, const _Float16* __restrict__ yB,
                               const float* __restrict__ b2, const int* __restrict__ t2i,
                               const float* __restrict__ t2w, const int* __restrict__ pslot,
                               float* __restrict__ out) {
    int t = blockIdx.x;
    int c = threadIdx.x * 4;
    int e0 = t2i[2 * t], e1 = t2i[2 * t + 1];
    float w0 = t2w[2 * t], w1 = t2w[2 * t + 1];
    size_t s0 = (size_t)pslot[2 * t] * D_OUT + c;
    size_t s1 = (size_t)pslot[2 * t + 1] * D_OUT + c;
    half4v a0 = *(const half4v*)(yA + s0);
    half4v b0 = *(const half4v*)(yB + s0);
    half4v a1 = *(const half4v*)(yA + s1);
    half4v b1v = *(const half4v*)(yB + s1);
    float4 bias0 = *(const float4*)(b2 + (size_t)e0 * D_OUT + c);
    float4 bias1 = *(const float4*)(b2 + (size_t)e1 * D_OUT + c);
    float4 o;
    o.x = w0 * ((float)a0[0] + (float)b0[0] + bias0.x) + w1 * ((float)a1[0] + (float)b1v[0] + bias1.x);
    o.y = w0 * ((float)a0[1] + (float)b0[1] + bias0.y) + w1 * ((float)a1[1] + (float)b1v[1] + bias1.y);
    o.z = w0 * ((float)a0[2] + (float)b0[2] + bias0.z) + w1 * ((float)a1[2] + (float)b1v[2] + bias1.z);
    o.w = w0 * ((float)a0[3] + (float)b0[3] + bias0.w) + w1 * ((float)a1[3] + (float)b1v[3] + bias1.w);
    *(float4*)(out + (size_t)t * D_OUT + c) = o;
}

extern "C" void kernel_launch(void* const* d_in, const int* in_sizes, int n_in,
                              void* d_out, int out_size, void* d_ws, size_t ws_size,
                              hipStream_t stream) {
    const float* x  = (const float*)d_in[0];
    const float* Wg = (const float*)d_in[1];
    const float* bg = (const float*)d_in[2];
    const float* W1 = (const float*)d_in[3];
    const float* b1 = (const float*)d_in[4];
    const float* W2 = (const float*)d_in[5];
    const float* b2 = (const float*)d_in[6];
    float* out = (float*)d_out;

    char* ws = (char*)d_ws;
    _Float16* xt     = (_Float16*)(ws);
    _Float16* Wt     = (_Float16*)(ws + 18874368ull);
    _Float16* ht     = (_Float16*)(ws + 52428800ull);
    _Float16* yA     = (_Float16*)(ws + 90177536ull);
    _Float16* yB     = (_Float16*)(ws + 109051904ull);
    int*      t2i    = (int*)(ws + 127926272ull);
    float*    t2w    = (float*)(ws + 127959040ull);
    int*      ptok   = (int*)(ws + 127991808ull);
    int*      pslot  = (int*)(ws + 128028672ull);
    int*      meta   = (int*)(ws + 128061440ull);
    int*      pcnt   = (int*)(ws + 128061952ull);
    float*    pusage = (float*)(ws + 128070144ull);
    int* cursor = meta + 8;

    hipMemsetAsync(meta, 0, 512, stream);

    gating_kernel<<<GB, 256, 0, stream>>>(x, Wg, bg, t2i, t2w, pcnt, pusage);
    scan_kernel<<<1, 64, 0, stream>>>(pcnt, pusage, meta, out + (size_t)BTOK * D_OUT);
    fill_kernel<<<36, 256, 0, stream>>>(ptok);
    scatter_kernel<<<16, 256, 0, stream>>>(t2i, cursor, ptok, pslot);
    gather_x_kernel<<<dim3(KT1, PT_MAX), 256, 0, stream>>>(x, ptok, xt);

    // half A: hidden [0, 2048)
    wtile_kernel<<<dim3(KT1, NT1, 8), 256, 0, stream>>>(W1, Wt, D_IN, D_HID, 0, 0, KT1, NT1);
    gemm1_kernel<<<dim3(PT_MAX, NT1), 256, 0, stream>>>(xt, Wt, b1, ht, meta, 0);
    wtile_kernel<<<dim3(KT2, NT2, 8), 256, 0, stream>>>(W2, Wt, D_HID, D_OUT, 0, 0, KT2, NT2);
    gemm2_kernel<<<dim3(PT_MAX, NT2), 256, 0, stream>>>(ht, Wt, yA, meta);

    // half B: hidden [2048, 4096)
    wtile_kernel<<<dim3(KT1, NT1, 8), 256, 0, stream>>>(W1, Wt, D_IN, D_HID, 0, HHALF, KT1, NT1);
    gemm1_kernel<<<dim3(PT_MAX, NT1), 256, 0, stream>>>(xt, Wt, b1, ht, meta, HHALF);
    wtile_kernel<<<dim3(KT2, NT2, 8), 256, 0, stream>>>(W2, Wt, D_HID, D_OUT, HHALF, 0, KT2, NT2);
    gemm2_kernel<<<dim3(PT_MAX, NT2), 256, 0, stream>>>(ht, Wt, yB, meta);

    combine_kernel<<<BTOK, 256, 0, stream>>>(yA, yB, b2, t2i, t2w, pslot, out);
}